// Round 1
// baseline (1696.882 us; speedup 1.0000x reference)
//
#include <hip/hip_runtime.h>
#include <math.h>

// BCAM: x1,x2 [8,192,128,128] f32. heads=8, c=24, temperature=0.01.
// Pipeline: out1=P(x1), out2=P(x2) -> norms -> attn(h-tokens), attn(w-tokens)
//           -> fusion (in d_out) -> P -> gelu(M1) -> M2 + x1 + x2 -> d_out.
// pos_bias dropped (per-head scalar, softmax shift-invariant).
// V = UNNORMALIZED tokens (v1=k1 binds before l2norm).

#define N_PIX 16384
#define W_DIM 128
#define C_DIM 192
#define C_PH  24
#define ELEMS 25165824  // 8*192*128*128
#define TINV  100.0f

// ---------------------------------------------------------------------------
// conv1x1 GEMM: Y[b,m,p] = act(sum_k Wt[m,k]*X[b,k,p] + bias[m]) (+R1+R2)
// grid (128 p-tiles, 3 m-tiles, 8 b), block 256. Tile 64m x 128p, 4x8/thread.
// MODE 0: plain  MODE 1: GELU(exact)  MODE 2: + R1 + R2 residual
// ---------------------------------------------------------------------------
template<int MODE>
__global__ __launch_bounds__(256)
void conv_kernel(const float* __restrict__ X, const float* __restrict__ Wt,
                 const float* __restrict__ bias, float* __restrict__ Y,
                 const float* __restrict__ R1, const float* __restrict__ R2)
{
    __shared__ __align__(16) float As[16][68];   // [k][m]
    __shared__ __align__(16) float Bs[16][132];  // [k][p]

    const int tid = threadIdx.x;
    const int p0 = blockIdx.x << 7;
    const int m0 = blockIdx.y << 6;
    const int b  = blockIdx.z;

    const float* Xb = X + (size_t)b * C_DIM * N_PIX;

    const int tx = tid & 15, ty = tid >> 4;
    const int arow = tid >> 2, acol = (tid & 3) << 2;   // A: 64 m rows x 16 k
    const int brow = tid >> 4, bcol = (tid & 15) << 2;  // B: 16 k rows x 128 p

    float acc[4][8] = {};

    for (int k0 = 0; k0 < C_DIM; k0 += 16) {
        const float4 av = *(const float4*)(Wt + (size_t)(m0 + arow) * C_DIM + (k0 + acol));
        const float4 b0 = *(const float4*)(Xb + (size_t)(k0 + brow) * N_PIX + (p0 + bcol));
        const float4 b1 = *(const float4*)(Xb + (size_t)(k0 + brow) * N_PIX + (p0 + bcol + 64));
        As[acol + 0][arow] = av.x;
        As[acol + 1][arow] = av.y;
        As[acol + 2][arow] = av.z;
        As[acol + 3][arow] = av.w;
        *(float4*)(&Bs[brow][bcol])      = b0;
        *(float4*)(&Bs[brow][bcol + 64]) = b1;
        __syncthreads();
        #pragma unroll
        for (int kk = 0; kk < 16; ++kk) {
            const float4 a4 = *(const float4*)(&As[kk][ty << 2]);
            const float4 p4 = *(const float4*)(&Bs[kk][tx << 2]);
            const float4 q4 = *(const float4*)(&Bs[kk][64 + (tx << 2)]);
            const float avv[4] = {a4.x, a4.y, a4.z, a4.w};
            const float bvv[8] = {p4.x, p4.y, p4.z, p4.w, q4.x, q4.y, q4.z, q4.w};
            #pragma unroll
            for (int mi = 0; mi < 4; ++mi)
                #pragma unroll
                for (int pi = 0; pi < 8; ++pi)
                    acc[mi][pi] += avv[mi] * bvv[pi];
        }
        __syncthreads();
    }

    const size_t outbase = (size_t)b * C_DIM * N_PIX;
    #pragma unroll
    for (int mi = 0; mi < 4; ++mi) {
        const int m = m0 + (ty << 2) + mi;
        const float bm = bias[m];
        const size_t row = outbase + (size_t)m * N_PIX + p0;
        #pragma unroll
        for (int half = 0; half < 2; ++half) {
            const int pc = (half << 6) + (tx << 2);
            float v[4];
            #pragma unroll
            for (int pi = 0; pi < 4; ++pi) v[pi] = acc[mi][(half << 2) + pi] + bm;
            if (MODE == 1) {
                #pragma unroll
                for (int pi = 0; pi < 4; ++pi)
                    v[pi] = 0.5f * v[pi] * (1.0f + erff(v[pi] * 0.70710678118654752f));
            }
            if (MODE == 2) {
                const float4 r1 = *(const float4*)(R1 + row + pc);
                const float4 r2 = *(const float4*)(R2 + row + pc);
                v[0] += r1.x + r2.x; v[1] += r1.y + r2.y;
                v[2] += r1.z + r2.z; v[3] += r1.w + r2.w;
            }
            float4 st = {v[0], v[1], v[2], v[3]};
            *(float4*)(Y + row + pc) = st;
        }
    }
}

// ---------------------------------------------------------------------------
// Token sum-of-squares. grid (8 b, 8 n, 8 = src*4+quarter), block 256.
// norms[src][b][n][dir*128+t] accumulates sumsq via global atomics (pre-zeroed).
// dir0: token=h (sum over ch,w); dir1: token=w (sum over ch,h).
// ---------------------------------------------------------------------------
__global__ __launch_bounds__(256)
void norms_kernel(const float* __restrict__ out1, const float* __restrict__ out2,
                  float* __restrict__ norms)
{
    __shared__ float hsum[128];
    __shared__ float wsum[128];
    const int tid = threadIdx.x;
    const int b = blockIdx.x, n = blockIdx.y;
    const int src = blockIdx.z >> 2, qt = blockIdx.z & 3;
    const float* basep = (src == 0 ? out1 : out2)
        + (size_t)b * C_DIM * N_PIX + (size_t)n * C_PH * N_PIX + (size_t)(qt * 6) * N_PIX;

    if (tid < 128) hsum[tid] = 0.0f;
    __syncthreads();

    const int tx = tid & 127, ty = tid >> 7;
    float accw = 0.0f;
    for (int hh = 0; hh < 64; ++hh) {
        const int h = (hh << 1) + ty;
        float rowacc = 0.0f;
        #pragma unroll
        for (int ch = 0; ch < 6; ++ch) {
            const float v = basep[(size_t)ch * N_PIX + h * W_DIM + tx];
            rowacc += v * v;
        }
        accw += rowacc;
        #pragma unroll
        for (int off = 32; off > 0; off >>= 1) rowacc += __shfl_down(rowacc, off);
        if ((tid & 63) == 0) atomicAdd(&hsum[h], rowacc);
    }
    if (ty == 0) wsum[tx] = accw;
    __syncthreads();
    if (ty == 1) wsum[tx] += accw;
    __syncthreads();

    float* np_ = norms + ((size_t)(src * 8 + b) * 8 + n) * 256;
    if (tid < 128) atomicAdd(&np_[tid], hsum[tid]);          // dir0 (h-tokens)
    else           atomicAdd(&np_[tid], wsum[tid - 128]);    // dir1 (w-tokens)
}

// ---------------------------------------------------------------------------
// Fused attention, one direction per launch (stream order makes dir1's RMW safe).
// grid (4 i-tiles, 64 b*n), block 256. i-tile = 32 tokens, full 128-token K/V.
// DIR0: tokens=h rows, Q=out2, K=V=out1, writes fusion = g*out3.
// DIR1: tokens=w cols, Q=out1, K=V=out2, fusion += (1-g)*out4.
// ---------------------------------------------------------------------------
template<int DIR>
__global__ __launch_bounds__(256)
void attn_kernel(const float* __restrict__ out1, const float* __restrict__ out2,
                 const float* __restrict__ norms, const float* __restrict__ gate,
                 float* __restrict__ fusion)
{
    // smem region: phase1 Qs[64][36] (2304) + Ks[64][132] (8448) = 10752 floats
    //              phase2 Vs[128][65] (8320) reuses it.
    __shared__ __align__(16) float smem[10752];
    __shared__ __align__(16) float Pt[128][36];  // transposed scores/probs [j][i]
    __shared__ float qn_s[32], kn_s[128];

    const int tid = threadIdx.x;
    const int i0 = blockIdx.x << 5;
    const int b = blockIdx.y >> 3, n = blockIdx.y & 7;

    const size_t base = (size_t)b * C_DIM * N_PIX + (size_t)n * C_PH * N_PIX;
    const float* Qb = (DIR == 0 ? out2 : out1) + base;
    const float* Kb = (DIR == 0 ? out1 : out2) + base;

    const int qsrc = (DIR == 0) ? 1 : 0;
    const float* qn_g = norms + ((size_t)(qsrc * 8 + b) * 8 + n) * 256 + DIR * 128;
    const float* kn_g = norms + ((size_t)((1 - qsrc) * 8 + b) * 8 + n) * 256 + DIR * 128;

    if (tid < 32)       qn_s[tid]      = TINV * rsqrtf(fmaxf(qn_g[i0 + tid], 1e-24f));
    else if (tid < 160) kn_s[tid - 32] = rsqrtf(fmaxf(kn_g[tid - 32], 1e-24f));
    __syncthreads();

    // ---- phase 1: S = Qraw . Kraw^T (32 x 128), K-dim = 24ch * 128x
    {
        const int im = tid >> 5;   // i = 4*im+ii
        const int jm = tid & 31;   // j = 4*jm+jj
        float acc[4][4] = {};

        for (int ch = 0; ch < C_PH; ++ch) {
            const float* Qc = Qb + (size_t)ch * N_PIX;
            const float* Kc = Kb + (size_t)ch * N_PIX;
            for (int x0 = 0; x0 < 128; x0 += 64) {
                if (DIR == 0) {
                    const int xc = (tid & 15) << 2;
                    #pragma unroll
                    for (int r = 0; r < 2; ++r) {
                        const int irow = (tid >> 4) + (r << 4);
                        const float4 qv = *(const float4*)(Qc + (size_t)(i0 + irow) * W_DIM + x0 + xc);
                        smem[(xc + 0) * 36 + irow] = qv.x;
                        smem[(xc + 1) * 36 + irow] = qv.y;
                        smem[(xc + 2) * 36 + irow] = qv.z;
                        smem[(xc + 3) * 36 + irow] = qv.w;
                    }
                    #pragma unroll
                    for (int r = 0; r < 8; ++r) {
                        const int jrow = (tid >> 4) + (r << 4);
                        const float4 kv = *(const float4*)(Kc + (size_t)jrow * W_DIM + x0 + xc);
                        smem[2304 + (xc + 0) * 132 + jrow] = kv.x;
                        smem[2304 + (xc + 1) * 132 + jrow] = kv.y;
                        smem[2304 + (xc + 2) * 132 + jrow] = kv.z;
                        smem[2304 + (xc + 3) * 132 + jrow] = kv.w;
                    }
                } else {
                    #pragma unroll
                    for (int r = 0; r < 2; ++r) {
                        const int xr = (tid >> 3) + (r << 5);
                        const int ic = (tid & 7) << 2;
                        const float4 qv = *(const float4*)(Qc + (size_t)(x0 + xr) * W_DIM + i0 + ic);
                        *(float4*)(&smem[xr * 36 + ic]) = qv;
                    }
                    #pragma unroll
                    for (int r = 0; r < 8; ++r) {
                        const int xr = (tid >> 5) + (r << 3);
                        const int jc = (tid & 31) << 2;
                        const float4 kv = *(const float4*)(Kc + (size_t)(x0 + xr) * W_DIM + jc);
                        *(float4*)(&smem[2304 + xr * 132 + jc]) = kv;
                    }
                }
                __syncthreads();
                #pragma unroll 8
                for (int kk = 0; kk < 64; ++kk) {
                    const float4 qv = *(const float4*)(&smem[kk * 36 + (im << 2)]);
                    const float4 kv = *(const float4*)(&smem[2304 + kk * 132 + (jm << 2)]);
                    const float qa[4] = {qv.x, qv.y, qv.z, qv.w};
                    const float ka[4] = {kv.x, kv.y, kv.z, kv.w};
                    #pragma unroll
                    for (int ii = 0; ii < 4; ++ii)
                        #pragma unroll
                        for (int jj = 0; jj < 4; ++jj)
                            acc[ii][jj] += qa[ii] * ka[jj];
                }
                __syncthreads();
            }
        }
        #pragma unroll
        for (int ii = 0; ii < 4; ++ii)
            #pragma unroll
            for (int jj = 0; jj < 4; ++jj) {
                const int i = (im << 2) + ii, j = (jm << 2) + jj;
                Pt[j][i] = acc[ii][jj] * qn_s[i] * kn_s[j];
            }
    }
    __syncthreads();

    // ---- softmax over j per row i (rows live in Pt columns)
    {
        const int wv = tid >> 6, lane = tid & 63;
        for (int r = 0; r < 8; ++r) {
            const int i = (wv << 3) + r;
            float v0 = Pt[lane][i], v1 = Pt[lane + 64][i];
            float m = fmaxf(v0, v1);
            #pragma unroll
            for (int off = 32; off > 0; off >>= 1) m = fmaxf(m, __shfl_xor(m, off));
            const float e0 = __expf(v0 - m), e1 = __expf(v1 - m);
            float s = e0 + e1;
            #pragma unroll
            for (int off = 32; off > 0; off >>= 1) s += __shfl_xor(s, off);
            const float inv = 1.0f / s;
            Pt[lane][i] = e0 * inv;
            Pt[lane + 64][i] = e1 * inv;
        }
    }
    __syncthreads();

    // ---- phase 2: O = P.V + q_normalized, scaled by gate, scatter to fusion
    const float g = 1.0f / (1.0f + __expf(-gate[0]));
    const float gs = (DIR == 0) ? g : (1.0f - g);
    const int ti = tid >> 5;   // i = 4*ti+q
    const int td = tid & 31;   // x = 2*td+e

    for (int ch = 0; ch < C_PH; ++ch) {
        const float* Vc = Kb + (size_t)ch * N_PIX;
        const float* Qc = Qb + (size_t)ch * N_PIX;
        float* Fc = fusion + base + (size_t)ch * N_PIX;
        for (int x0 = 0; x0 < 128; x0 += 64) {
            if (DIR == 0) {
                const int xc = (tid & 15) << 2;
                #pragma unroll
                for (int r = 0; r < 8; ++r) {
                    const int j = (tid >> 4) + (r << 4);
                    const float4 vv = *(const float4*)(Vc + (size_t)j * W_DIM + x0 + xc);
                    smem[j * 65 + xc + 0] = vv.x;
                    smem[j * 65 + xc + 1] = vv.y;
                    smem[j * 65 + xc + 2] = vv.z;
                    smem[j * 65 + xc + 3] = vv.w;
                }
            } else {
                const int jj = tid & 127, xh = tid >> 7;
                #pragma unroll 8
                for (int r = 0; r < 32; ++r) {
                    const int x = xh + (r << 1);
                    smem[jj * 65 + x] = Vc[(size_t)(x0 + x) * W_DIM + jj];
                }
            }
            __syncthreads();

            float a2[4][2] = {};
            #pragma unroll 8
            for (int j = 0; j < 128; ++j) {
                const float4 p = *(const float4*)(&Pt[j][ti << 2]);
                const float vx0 = smem[j * 65 + (td << 1)];
                const float vx1 = smem[j * 65 + (td << 1) + 1];
                a2[0][0] += p.x * vx0; a2[0][1] += p.x * vx1;
                a2[1][0] += p.y * vx0; a2[1][1] += p.y * vx1;
                a2[2][0] += p.z * vx0; a2[2][1] += p.z * vx1;
                a2[3][0] += p.w * vx0; a2[3][1] += p.w * vx1;
            }

            #pragma unroll
            for (int q = 0; q < 4; ++q) {
                const int i = i0 + (ti << 2) + q;
                const float invq = qn_s[(ti << 2) + q] * 0.01f;  // = 1/||q_i||
                if (DIR == 0) {
                    const float2 qr = *(const float2*)(Qc + (size_t)i * W_DIM + x0 + (td << 1));
                    float2 st;
                    st.x = gs * (a2[q][0] + qr.x * invq);
                    st.y = gs * (a2[q][1] + qr.y * invq);
                    *(float2*)(Fc + (size_t)i * W_DIM + x0 + (td << 1)) = st;
                } else {
                    #pragma unroll
                    for (int e = 0; e < 2; ++e) {
                        const int xg = x0 + (td << 1) + e;
                        const float qraw = Qc[(size_t)xg * W_DIM + i];
                        const float v = gs * (a2[q][e] + qraw * invq);
                        Fc[(size_t)xg * W_DIM + i] += v;
                    }
                }
            }
            __syncthreads();
        }
    }
}

// ---------------------------------------------------------------------------
extern "C" void kernel_launch(void* const* d_in, const int* in_sizes, int n_in,
                              void* d_out, int out_size, void* d_ws, size_t ws_size,
                              hipStream_t stream)
{
    (void)in_sizes; (void)n_in; (void)out_size; (void)ws_size;
    const float* x1     = (const float*)d_in[0];
    const float* x2     = (const float*)d_in[1];
    const float* W_proj = (const float*)d_in[2];
    const float* b_proj = (const float*)d_in[3];
    const float* gate   = (const float*)d_in[4];
    // d_in[5], d_in[6]: pos_bias_h/w — per-head scalars, cancel in softmax.
    const float* W_m1   = (const float*)d_in[7];
    const float* b_m1   = (const float*)d_in[8];
    const float* W_m2   = (const float*)d_in[9];
    const float* b_m2   = (const float*)d_in[10];

    float* ws0    = (float*)d_ws;        // out1, later t1
    float* ws1    = ws0 + ELEMS;         // out2, later t2
    float* norms  = ws1 + ELEMS;         // 32768 floats of sumsq
    float* fusion = (float*)d_out;       // scratch until final conv overwrites

    const dim3 cgrid(128, 3, 8);
    conv_kernel<0><<<cgrid, 256, 0, stream>>>(x1, W_proj, b_proj, ws0, nullptr, nullptr);
    conv_kernel<0><<<cgrid, 256, 0, stream>>>(x2, W_proj, b_proj, ws1, nullptr, nullptr);

    hipMemsetAsync(norms, 0, 32768 * sizeof(float), stream);
    norms_kernel<<<dim3(8, 8, 8), 256, 0, stream>>>(ws0, ws1, norms);

    attn_kernel<0><<<dim3(4, 64), 256, 0, stream>>>(ws0, ws1, norms, gate, fusion);
    attn_kernel<1><<<dim3(4, 64), 256, 0, stream>>>(ws0, ws1, norms, gate, fusion);

    conv_kernel<0><<<cgrid, 256, 0, stream>>>(fusion, W_proj, b_proj, ws0, nullptr, nullptr);
    conv_kernel<1><<<cgrid, 256, 0, stream>>>(ws0, W_m1, b_m1, ws1, nullptr, nullptr);
    conv_kernel<2><<<cgrid, 256, 0, stream>>>(ws1, W_m2, b_m2, (float*)d_out, x1, x2);
}

// Round 2
// 1523.438 us; speedup vs baseline: 1.1139x; 1.1139x over previous
//
#include <hip/hip_runtime.h>
#include <math.h>

// BCAM: x1,x2 [8,192,128,128] f32. heads=8, c=24, temperature=0.01.
// R2 structure:
//   conv1: out1=P(x1)->ws0   conv2: out2=P(x2)->ws1
//   norms_kernel -> sumsq per token (ws tail)
//   scores: partial S = Qraw.Kraw^T, 4 k-chunks, -> d_out[0..32MB)
//   softmaxk: sum partials, scale 100*rq*rk, softmax, pre-scale by g/(1-g) -> P in d_out[32..40MB)
//   pv_fusion: fusion = g*(P1@A1) + (1-g)*(A2@P2^T) + g*rq1[h]*A2 + (1-g)*rq2[w]*A1, in-place over ws0
//   conv5: P(fusion)->ws1   conv6: gelu(M1(ws1))->ws0   conv7: M2(ws0)+x1+x2 -> d_out
// pos_bias dropped (per-head scalar, softmax shift-invariant).
// V = UNNORMALIZED tokens (v1=k1 binds before l2norm).

#define N_PIX 16384
#define W_DIM 128
#define C_DIM 192
#define C_PH  24
#define ELEMS 25165824  // 8*192*128*128
#define TINV  100.0f

// ---------------------------------------------------------------------------
// conv1x1 GEMM: Y[b,m,p] = act(sum_k Wt[m,k]*X[b,k,p] + bias[m]) (+R1+R2)
// ---------------------------------------------------------------------------
template<int MODE>
__global__ __launch_bounds__(256)
void conv_kernel(const float* __restrict__ X, const float* __restrict__ Wt,
                 const float* __restrict__ bias, float* __restrict__ Y,
                 const float* __restrict__ R1, const float* __restrict__ R2)
{
    __shared__ __align__(16) float As[16][68];   // [k][m]
    __shared__ __align__(16) float Bs[16][132];  // [k][p]

    const int tid = threadIdx.x;
    const int p0 = blockIdx.x << 7;
    const int m0 = blockIdx.y << 6;
    const int b  = blockIdx.z;

    const float* Xb = X + (size_t)b * C_DIM * N_PIX;

    const int tx = tid & 15, ty = tid >> 4;
    const int arow = tid >> 2, acol = (tid & 3) << 2;
    const int brow = tid >> 4, bcol = (tid & 15) << 2;

    float acc[4][8] = {};

    for (int k0 = 0; k0 < C_DIM; k0 += 16) {
        const float4 av = *(const float4*)(Wt + (size_t)(m0 + arow) * C_DIM + (k0 + acol));
        const float4 b0 = *(const float4*)(Xb + (size_t)(k0 + brow) * N_PIX + (p0 + bcol));
        const float4 b1 = *(const float4*)(Xb + (size_t)(k0 + brow) * N_PIX + (p0 + bcol + 64));
        As[acol + 0][arow] = av.x;
        As[acol + 1][arow] = av.y;
        As[acol + 2][arow] = av.z;
        As[acol + 3][arow] = av.w;
        *(float4*)(&Bs[brow][bcol])      = b0;
        *(float4*)(&Bs[brow][bcol + 64]) = b1;
        __syncthreads();
        #pragma unroll
        for (int kk = 0; kk < 16; ++kk) {
            const float4 a4 = *(const float4*)(&As[kk][ty << 2]);
            const float4 p4 = *(const float4*)(&Bs[kk][tx << 2]);
            const float4 q4 = *(const float4*)(&Bs[kk][64 + (tx << 2)]);
            const float avv[4] = {a4.x, a4.y, a4.z, a4.w};
            const float bvv[8] = {p4.x, p4.y, p4.z, p4.w, q4.x, q4.y, q4.z, q4.w};
            #pragma unroll
            for (int mi = 0; mi < 4; ++mi)
                #pragma unroll
                for (int pi = 0; pi < 8; ++pi)
                    acc[mi][pi] += avv[mi] * bvv[pi];
        }
        __syncthreads();
    }

    const size_t outbase = (size_t)b * C_DIM * N_PIX;
    #pragma unroll
    for (int mi = 0; mi < 4; ++mi) {
        const int m = m0 + (ty << 2) + mi;
        const float bm = bias[m];
        const size_t row = outbase + (size_t)m * N_PIX + p0;
        #pragma unroll
        for (int half = 0; half < 2; ++half) {
            const int pc = (half << 6) + (tx << 2);
            float v[4];
            #pragma unroll
            for (int pi = 0; pi < 4; ++pi) v[pi] = acc[mi][(half << 2) + pi] + bm;
            if (MODE == 1) {
                #pragma unroll
                for (int pi = 0; pi < 4; ++pi)
                    v[pi] = 0.5f * v[pi] * (1.0f + erff(v[pi] * 0.70710678118654752f));
            }
            if (MODE == 2) {
                const float4 r1 = *(const float4*)(R1 + row + pc);
                const float4 r2 = *(const float4*)(R2 + row + pc);
                v[0] += r1.x + r2.x; v[1] += r1.y + r2.y;
                v[2] += r1.z + r2.z; v[3] += r1.w + r2.w;
            }
            float4 st = {v[0], v[1], v[2], v[3]};
            *(float4*)(Y + row + pc) = st;
        }
    }
}

// ---------------------------------------------------------------------------
// Token sum-of-squares. norms[src][b][n][dir*128+t], atomic accumulate.
// ---------------------------------------------------------------------------
__global__ __launch_bounds__(256)
void norms_kernel(const float* __restrict__ out1, const float* __restrict__ out2,
                  float* __restrict__ norms)
{
    __shared__ float hsum[128];
    __shared__ float wsum[128];
    const int tid = threadIdx.x;
    const int b = blockIdx.x, n = blockIdx.y;
    const int src = blockIdx.z >> 2, qt = blockIdx.z & 3;
    const float* basep = (src == 0 ? out1 : out2)
        + (size_t)b * C_DIM * N_PIX + (size_t)n * C_PH * N_PIX + (size_t)(qt * 6) * N_PIX;

    if (tid < 128) hsum[tid] = 0.0f;
    __syncthreads();

    const int tx = tid & 127, ty = tid >> 7;
    float accw = 0.0f;
    for (int hh = 0; hh < 64; ++hh) {
        const int h = (hh << 1) + ty;
        float rowacc = 0.0f;
        #pragma unroll
        for (int ch = 0; ch < 6; ++ch) {
            const float v = basep[(size_t)ch * N_PIX + h * W_DIM + tx];
            rowacc += v * v;
        }
        accw += rowacc;
        #pragma unroll
        for (int off = 32; off > 0; off >>= 1) rowacc += __shfl_down(rowacc, off);
        if ((tid & 63) == 0) atomicAdd(&hsum[h], rowacc);
    }
    if (ty == 0) wsum[tx] = accw;
    __syncthreads();
    if (ty == 1) wsum[tx] += accw;
    __syncthreads();

    float* np_ = norms + ((size_t)(src * 8 + b) * 8 + n) * 256;
    if (tid < 128) atomicAdd(&np_[tid], hsum[tid]);
    else           atomicAdd(&np_[tid], wsum[tid - 128]);
}

// ---------------------------------------------------------------------------
// scores: partial raw S. grid (4 kc, 64 bn, 2 dir), block 256, 8x8/thread.
// Spart[kc][dir][bn][i][j] (d_out scratch). k-chunk = 6 channels (768 dims).
// ---------------------------------------------------------------------------
__global__ __launch_bounds__(256)
void scores_kernel(const float* __restrict__ out1, const float* __restrict__ out2,
                   float* __restrict__ Spart)
{
    __shared__ __align__(16) float Qs[16][132];
    __shared__ __align__(16) float Ks[16][132];

    const int tid = threadIdx.x;
    const int kc  = blockIdx.x;
    const int bn  = blockIdx.y;
    const int dir = blockIdx.z;
    const int b = bn >> 3, n = bn & 7;

    const size_t base = (size_t)b * C_DIM * N_PIX + (size_t)n * C_PH * N_PIX;
    const float* Qt = (dir == 0 ? out2 : out1) + base;
    const float* Kt = (dir == 0 ? out1 : out2) + base;

    const int ti = tid & 15, tj = tid >> 4;
    float acc[8][8] = {};

    for (int kt = 0; kt < 48; ++kt) {
        const int ch = kc * 6 + (kt >> 3);
        const int x0 = (kt & 7) << 4;
        const float* Qc = Qt + (size_t)ch * N_PIX;
        const float* Kc = Kt + (size_t)ch * N_PIX;

        if (dir == 0) {
            // token = h-row; feature along w: transpose into [k][token]
            const int ib = tid >> 2, xg = (tid & 3) << 2;
            #pragma unroll
            for (int r = 0; r < 2; ++r) {
                const int ii = ib + (r << 6);
                const float4 q = *(const float4*)(Qc + (size_t)ii * W_DIM + x0 + xg);
                Qs[xg + 0][ii] = q.x; Qs[xg + 1][ii] = q.y;
                Qs[xg + 2][ii] = q.z; Qs[xg + 3][ii] = q.w;
                const float4 k = *(const float4*)(Kc + (size_t)ii * W_DIM + x0 + xg);
                Ks[xg + 0][ii] = k.x; Ks[xg + 1][ii] = k.y;
                Ks[xg + 2][ii] = k.z; Ks[xg + 3][ii] = k.w;
            }
        } else {
            // token = w-col; feature along h: rows are already [k][token]
            const int kk = tid >> 5, ic = (tid & 31) << 2;
            #pragma unroll
            for (int r = 0; r < 2; ++r) {
                const int kr = kk + (r << 3);
                *(float4*)(&Qs[kr][ic]) = *(const float4*)(Qt + (size_t)ch * N_PIX + (size_t)(x0 + kr) * W_DIM + ic);
                *(float4*)(&Ks[kr][ic]) = *(const float4*)(Kt + (size_t)ch * N_PIX + (size_t)(x0 + kr) * W_DIM + ic);
            }
        }
        __syncthreads();

        #pragma unroll
        for (int kk = 0; kk < 16; ++kk) {
            float qa[8], ka[8];
            *(float4*)(&qa[0]) = *(const float4*)(&Qs[kk][(ti << 3) + 0]);
            *(float4*)(&qa[4]) = *(const float4*)(&Qs[kk][(ti << 3) + 4]);
            *(float4*)(&ka[0]) = *(const float4*)(&Ks[kk][(tj << 3) + 0]);
            *(float4*)(&ka[4]) = *(const float4*)(&Ks[kk][(tj << 3) + 4]);
            #pragma unroll
            for (int ii = 0; ii < 8; ++ii)
                #pragma unroll
                for (int jj = 0; jj < 8; ++jj)
                    acc[ii][jj] += qa[ii] * ka[jj];
        }
        __syncthreads();
    }

    float* Sp = Spart + ((((size_t)kc * 2 + dir) * 64 + bn) << 14);
    #pragma unroll
    for (int ii = 0; ii < 8; ++ii) {
        const int i = (ti << 3) + ii;
        *(float4*)(Sp + (size_t)i * 128 + (tj << 3) + 0) = *(float4*)(&acc[ii][0]);
        *(float4*)(Sp + (size_t)i * 128 + (tj << 3) + 4) = *(float4*)(&acc[ii][4]);
    }
}

// ---------------------------------------------------------------------------
// softmax: sum 4 partials, scale 100*rq[i]*rk[j], softmax rows, pre-scale by
// gate weight, write P. grid (16 rowgroups, 64 bn, 2 dir), block 256 (8 rows).
// ---------------------------------------------------------------------------
__global__ __launch_bounds__(256)
void softmax_kernel(const float* __restrict__ Spart, float* __restrict__ P,
                    const float* __restrict__ norms, const float* __restrict__ gate)
{
    const int tid = threadIdx.x;
    const int bn  = blockIdx.y;
    const int dir = blockIdx.z;
    const int b = bn >> 3, n = bn & 7;

    const int r  = tid >> 5;
    const int j0 = (tid & 31) << 2;
    const int i  = (blockIdx.x << 3) + r;

    const int qsrc = (dir == 0) ? 1 : 0;
    const float* qn = norms + (((size_t)qsrc * 8 + b) * 8 + n) * 256 + dir * 128;
    const float* kn = norms + (((size_t)(1 - qsrc) * 8 + b) * 8 + n) * 256 + dir * 128;

    const float crow = TINV * rsqrtf(fmaxf(qn[i], 1e-24f));
    float rk[4];
    #pragma unroll
    for (int e = 0; e < 4; ++e) rk[e] = rsqrtf(fmaxf(kn[j0 + e], 1e-24f));

    const size_t off = ((size_t)dir * 64 + bn) * 16384 + (size_t)i * 128 + j0;
    float4 s = *(const float4*)(Spart + off);
    #pragma unroll
    for (int kc = 1; kc < 4; ++kc) {
        const float4 t = *(const float4*)(Spart + ((size_t)kc * 2 * 64 << 14) + off);
        s.x += t.x; s.y += t.y; s.z += t.z; s.w += t.w;
    }
    float v[4] = {s.x * crow * rk[0], s.y * crow * rk[1],
                  s.z * crow * rk[2], s.w * crow * rk[3]};

    float m = fmaxf(fmaxf(v[0], v[1]), fmaxf(v[2], v[3]));
    #pragma unroll
    for (int off2 = 16; off2 > 0; off2 >>= 1) m = fmaxf(m, __shfl_xor(m, off2));
    float e4[4], sum = 0.0f;
    #pragma unroll
    for (int e = 0; e < 4; ++e) { e4[e] = __expf(v[e] - m); sum += e4[e]; }
    #pragma unroll
    for (int off2 = 16; off2 > 0; off2 >>= 1) sum += __shfl_xor(sum, off2);

    const float g = 1.0f / (1.0f + __expf(-gate[0]));
    const float gs = (dir == 0) ? g : (1.0f - g);
    const float inv = gs / sum;

    float4 p = {e4[0] * inv, e4[1] * inv, e4[2] * inv, e4[3] * inv};
    *(float4*)(P + ((size_t)dir * 64 + bn) * 16384 + (size_t)i * 128 + j0) = p;
}

// ---------------------------------------------------------------------------
// pv_fusion: per (ch, bn) channel plane, both directions fused:
//   F[h,w] = P1g[h,:]@A1[:,w] + A2[h,:]@P2g[w,:] + g*rq1[h]*A2[h,w] + (1-g)*rq2[w]*A1[h,w]
// (P1g/P2g already carry the g / (1-g) factor from softmax_kernel.)
// Written IN PLACE over out1's plane (each plane touched by exactly one block).
// grid (24 ch, 64 bn), block 256, 8x8 outputs/thread, K-tiles of 16.
// ---------------------------------------------------------------------------
__global__ __launch_bounds__(256)
void pv_fusion_kernel(float* __restrict__ out1, const float* __restrict__ out2,
                      const float* __restrict__ P, const float* __restrict__ norms,
                      const float* __restrict__ gate)
{
    __shared__ __align__(16) float P1t[16][132];
    __shared__ __align__(16) float A1s[16][132];
    __shared__ __align__(16) float A2t[16][132];
    __shared__ __align__(16) float P2t[16][132];
    __shared__ float rqs[256];

    const int tid = threadIdx.x;
    const int ch  = blockIdx.x;
    const int bn  = blockIdx.y;
    const int b = bn >> 3, n = bn & 7;

    const size_t pbase = (size_t)b * C_DIM * N_PIX + ((size_t)n * C_PH + ch) * N_PIX;
    float* A1 = out1 + pbase;
    const float* A2 = out2 + pbase;
    const float* P1 = P + ((size_t)bn << 14);
    const float* P2 = P + ((size_t)(64 + bn) << 14);

    const float g = 1.0f / (1.0f + __expf(-gate[0]));
    if (tid < 128)
        rqs[tid] = g * rsqrtf(fmaxf(norms[(((size_t)1 * 8 + b) * 8 + n) * 256 + tid], 1e-24f));
    else
        rqs[tid] = (1.0f - g) * rsqrtf(fmaxf(norms[(((size_t)0 * 8 + b) * 8 + n) * 256 + 128 + (tid - 128)], 1e-24f));

    const int ti = tid & 15, tj = tid >> 4;
    float acc[8][8] = {};

    for (int kt = 0; kt < 8; ++kt) {
        const int k0 = kt << 4;
        {
            const int rr = tid >> 2, xg = (tid & 3) << 2;
            #pragma unroll
            for (int r = 0; r < 2; ++r) {
                const int i = rr + (r << 6);
                float4 v;
                v = *(const float4*)(P1 + (size_t)i * 128 + k0 + xg);
                P1t[xg + 0][i] = v.x; P1t[xg + 1][i] = v.y;
                P1t[xg + 2][i] = v.z; P1t[xg + 3][i] = v.w;
                v = *(const float4*)(A2 + (size_t)i * 128 + k0 + xg);
                A2t[xg + 0][i] = v.x; A2t[xg + 1][i] = v.y;
                A2t[xg + 2][i] = v.z; A2t[xg + 3][i] = v.w;
                v = *(const float4*)(P2 + (size_t)i * 128 + k0 + xg);
                P2t[xg + 0][i] = v.x; P2t[xg + 1][i] = v.y;
                P2t[xg + 2][i] = v.z; P2t[xg + 3][i] = v.w;
            }
            const int kk = tid >> 5, wc = (tid & 31) << 2;
            #pragma unroll
            for (int r = 0; r < 2; ++r) {
                const int kr = kk + (r << 3);
                *(float4*)(&A1s[kr][wc]) = *(const float4*)(A1 + (size_t)(k0 + kr) * 128 + wc);
            }
        }
        __syncthreads();

        #pragma unroll
        for (int kk = 0; kk < 16; ++kk) {
            float p1[8], a1[8], a2[8], p2[8];
            *(float4*)(&p1[0]) = *(const float4*)(&P1t[kk][(ti << 3) + 0]);
            *(float4*)(&p1[4]) = *(const float4*)(&P1t[kk][(ti << 3) + 4]);
            *(float4*)(&a2[0]) = *(const float4*)(&A2t[kk][(ti << 3) + 0]);
            *(float4*)(&a2[4]) = *(const float4*)(&A2t[kk][(ti << 3) + 4]);
            *(float4*)(&a1[0]) = *(const float4*)(&A1s[kk][(tj << 3) + 0]);
            *(float4*)(&a1[4]) = *(const float4*)(&A1s[kk][(tj << 3) + 4]);
            *(float4*)(&p2[0]) = *(const float4*)(&P2t[kk][(tj << 3) + 0]);
            *(float4*)(&p2[4]) = *(const float4*)(&P2t[kk][(tj << 3) + 4]);
            #pragma unroll
            for (int ii = 0; ii < 8; ++ii)
                #pragma unroll
                for (int jj = 0; jj < 8; ++jj)
                    acc[ii][jj] += p1[ii] * a1[jj] + a2[ii] * p2[jj];
        }
        __syncthreads();
    }

    #pragma unroll
    for (int ii = 0; ii < 8; ++ii) {
        const int i = (ti << 3) + ii;
        const float c1 = rqs[i];
        #pragma unroll
        for (int jh = 0; jh < 2; ++jh) {
            const int j = (tj << 3) + (jh << 2);
            const float4 a1v = *(const float4*)(A1 + (size_t)i * 128 + j);
            const float4 a2v = *(const float4*)(A2 + (size_t)i * 128 + j);
            float4 o;
            o.x = acc[ii][(jh << 2) + 0] + c1 * a2v.x + rqs[128 + j + 0] * a1v.x;
            o.y = acc[ii][(jh << 2) + 1] + c1 * a2v.y + rqs[128 + j + 1] * a1v.y;
            o.z = acc[ii][(jh << 2) + 2] + c1 * a2v.z + rqs[128 + j + 2] * a1v.z;
            o.w = acc[ii][(jh << 2) + 3] + c1 * a2v.w + rqs[128 + j + 3] * a1v.w;
            *(float4*)(A1 + (size_t)i * 128 + j) = o;
        }
    }
}

// ---------------------------------------------------------------------------
extern "C" void kernel_launch(void* const* d_in, const int* in_sizes, int n_in,
                              void* d_out, int out_size, void* d_ws, size_t ws_size,
                              hipStream_t stream)
{
    (void)in_sizes; (void)n_in; (void)out_size; (void)ws_size;
    const float* x1     = (const float*)d_in[0];
    const float* x2     = (const float*)d_in[1];
    const float* W_proj = (const float*)d_in[2];
    const float* b_proj = (const float*)d_in[3];
    const float* gate   = (const float*)d_in[4];
    // d_in[5], d_in[6]: pos_bias_h/w — per-head scalars, cancel in softmax.
    const float* W_m1   = (const float*)d_in[7];
    const float* b_m1   = (const float*)d_in[8];
    const float* W_m2   = (const float*)d_in[9];
    const float* b_m2   = (const float*)d_in[10];

    float* ws0   = (float*)d_ws;          // out1 -> fusion (in place) -> t2
    float* ws1   = ws0 + ELEMS;           // out2 -> t1
    float* norms = ws1 + ELEMS;           // 32768 floats sumsq

    float* Spart = (float*)d_out;         // 4*2*64*16384 = 8388608 floats (32MB)
    float* Pbuf  = Spart + 8388608;       // 2*64*16384   = 2097152 floats (8MB)

    const dim3 cgrid(128, 3, 8);
    conv_kernel<0><<<cgrid, 256, 0, stream>>>(x1, W_proj, b_proj, ws0, nullptr, nullptr);
    conv_kernel<0><<<cgrid, 256, 0, stream>>>(x2, W_proj, b_proj, ws1, nullptr, nullptr);

    hipMemsetAsync(norms, 0, 32768 * sizeof(float), stream);
    norms_kernel<<<dim3(8, 8, 8), 256, 0, stream>>>(ws0, ws1, norms);

    scores_kernel<<<dim3(4, 64, 2), 256, 0, stream>>>(ws0, ws1, Spart);
    softmax_kernel<<<dim3(16, 64, 2), 256, 0, stream>>>(Spart, Pbuf, norms, gate);
    pv_fusion_kernel<<<dim3(24, 64), 256, 0, stream>>>(ws0, ws1, Pbuf, norms, gate);

    conv_kernel<0><<<cgrid, 256, 0, stream>>>(ws0, W_proj, b_proj, ws1, nullptr, nullptr);
    conv_kernel<1><<<cgrid, 256, 0, stream>>>(ws1, W_m1, b_m1, ws0, nullptr, nullptr);
    conv_kernel<2><<<cgrid, 256, 0, stream>>>(ws0, W_m2, b_m2, (float*)d_out, x1, x2);
}

// Round 3
// 841.721 us; speedup vs baseline: 2.0160x; 1.8099x over previous
//
#include <hip/hip_runtime.h>
#include <math.h>

// BCAM: x1,x2 [8,192,128,128] f32. heads=8, c=24, temperature=0.01.
// R3: MFMA everywhere except scores/softmax/norms.
//   conv1/2: split-bf16 (hi+lo, 3 MFMA passes) — feeds 100x-amplified logits.
//   pv + conv5/6/7: plain bf16 MFMA, fp32 accumulate.
// pos_bias dropped (per-head scalar, softmax shift-invariant).
// V = UNNORMALIZED tokens (v1=k1 binds before l2norm).

#define N_PIX 16384
#define W_DIM 128
#define C_DIM 192
#define C_PH  24
#define ELEMS 25165824  // 8*192*128*128
#define TINV  100.0f

typedef __bf16 bf16x8 __attribute__((ext_vector_type(8)));
typedef float  f32x4  __attribute__((ext_vector_type(4)));

__device__ __forceinline__ unsigned short f2bf(float f) {
    union { float f; unsigned u; } x; x.f = f;
    unsigned r = x.u + 0x7FFF + ((x.u >> 16) & 1);
    return (unsigned short)(r >> 16);
}
__device__ __forceinline__ float bf2f(unsigned short h) {
    union { unsigned u; float f; } x; x.u = ((unsigned)h) << 16; return x.f;
}
__device__ __forceinline__ unsigned pack2(unsigned short a, unsigned short b) {
    return (unsigned)a | ((unsigned)b << 16);
}

// ---------------------------------------------------------------------------
// conv1x1 via bf16 MFMA. Y[b,m,p] = act(sum_k Wt[m,k]*X[b,k,p] + bias[m]).
// grid (64 p-tiles, 3 m-tiles, 8 b), block 256 (4 waves). Tile 64m x 256p.
// Weights = A-operand [m][k] (k-contig). Pixels = B-operand: 4x4 register
// transpose into LDS [p][k]. SPLIT=1: hi+lo bf16 decomposition, 3 MFMAs.
// MODE 0: plain  MODE 1: GELU(exact)  MODE 2: + R1 + R2 residual
// ---------------------------------------------------------------------------
template<int MODE, int SPLIT>
__global__ __launch_bounds__(256)
void conv_mfma(const float* __restrict__ X, const float* __restrict__ Wt,
               const float* __restrict__ bias, float* __restrict__ Y,
               const float* __restrict__ R1, const float* __restrict__ R2)
{
    __shared__ unsigned short Ah[64][40];
    __shared__ unsigned short Bh[256][40];
    __shared__ unsigned short Al[SPLIT ? 64 : 1][40];
    __shared__ unsigned short Bl[SPLIT ? 256 : 1][40];

    const int tid = threadIdx.x;
    const int p0 = blockIdx.x << 8;
    const int m0 = blockIdx.y << 6;
    const int b  = blockIdx.z;
    const float* Xb = X + (size_t)b * C_DIM * N_PIX;

    const int wave = tid >> 6, lane = tid & 63;
    const int quad = lane >> 4, l16 = lane & 15;
    const int mw = (wave & 1) << 5;   // 0/32
    const int nw = (wave >> 1) << 7;  // 0/128
    const int koff = quad << 3;

    f32x4 acc[2][8];
    #pragma unroll
    for (int i = 0; i < 2; ++i)
        #pragma unroll
        for (int j = 0; j < 8; ++j) acc[i][j] = (f32x4){0.f, 0.f, 0.f, 0.f};

    for (int k0 = 0; k0 < C_DIM; k0 += 32) {
        // ---- stage A (weights) 64x32
        #pragma unroll
        for (int i = 0; i < 2; ++i) {
            const int a = (tid << 1) + i;
            const int m = a >> 3, kq = a & 7;
            const float4 v = *(const float4*)(Wt + (size_t)(m0 + m) * C_DIM + k0 + (kq << 2));
            const unsigned short h0 = f2bf(v.x), h1 = f2bf(v.y), h2 = f2bf(v.z), h3 = f2bf(v.w);
            uint2 pk; pk.x = pack2(h0, h1); pk.y = pack2(h2, h3);
            *(uint2*)(&Ah[m][kq << 2]) = pk;
            if (SPLIT) {
                uint2 pl;
                pl.x = pack2(f2bf(v.x - bf2f(h0)), f2bf(v.y - bf2f(h1)));
                pl.y = pack2(f2bf(v.z - bf2f(h2)), f2bf(v.w - bf2f(h3)));
                *(uint2*)(&Al[m][kq << 2]) = pl;
            }
        }
        // ---- stage B (pixels) 32k x 256p with 4x4 transpose
        #pragma unroll
        for (int r = 0; r < 2; ++r) {
            const int u = tid + (r << 8);
            const int kq = u >> 6, p4 = (u & 63) << 2;
            float4 f[4];
            #pragma unroll
            for (int i = 0; i < 4; ++i)
                f[i] = *(const float4*)(Xb + (size_t)(k0 + (kq << 2) + i) * N_PIX + p0 + p4);
            #pragma unroll
            for (int j = 0; j < 4; ++j) {
                const float e0 = (&f[0].x)[j], e1 = (&f[1].x)[j];
                const float e2 = (&f[2].x)[j], e3 = (&f[3].x)[j];
                const unsigned short h0 = f2bf(e0), h1 = f2bf(e1);
                const unsigned short h2 = f2bf(e2), h3 = f2bf(e3);
                uint2 pk; pk.x = pack2(h0, h1); pk.y = pack2(h2, h3);
                *(uint2*)(&Bh[p4 + j][kq << 2]) = pk;
                if (SPLIT) {
                    uint2 pl;
                    pl.x = pack2(f2bf(e0 - bf2f(h0)), f2bf(e1 - bf2f(h1)));
                    pl.y = pack2(f2bf(e2 - bf2f(h2)), f2bf(e3 - bf2f(h3)));
                    *(uint2*)(&Bl[p4 + j][kq << 2]) = pl;
                }
            }
        }
        __syncthreads();

        bf16x8 af[2], al[2];
        #pragma unroll
        for (int mf = 0; mf < 2; ++mf) {
            af[mf] = *(const bf16x8*)(&Ah[mw + (mf << 4) + l16][koff]);
            if (SPLIT) al[mf] = *(const bf16x8*)(&Al[mw + (mf << 4) + l16][koff]);
        }
        #pragma unroll
        for (int nf = 0; nf < 8; ++nf) {
            const bf16x8 bfr = *(const bf16x8*)(&Bh[nw + (nf << 4) + l16][koff]);
            bf16x8 blr;
            if (SPLIT) blr = *(const bf16x8*)(&Bl[nw + (nf << 4) + l16][koff]);
            #pragma unroll
            for (int mf = 0; mf < 2; ++mf) {
                acc[mf][nf] = __builtin_amdgcn_mfma_f32_16x16x32_bf16(af[mf], bfr, acc[mf][nf], 0, 0, 0);
                if (SPLIT) {
                    acc[mf][nf] = __builtin_amdgcn_mfma_f32_16x16x32_bf16(al[mf], bfr, acc[mf][nf], 0, 0, 0);
                    acc[mf][nf] = __builtin_amdgcn_mfma_f32_16x16x32_bf16(af[mf], blr, acc[mf][nf], 0, 0, 0);
                }
            }
        }
        __syncthreads();
    }

    const size_t outb = (size_t)b * C_DIM * N_PIX;
    #pragma unroll
    for (int mf = 0; mf < 2; ++mf) {
        #pragma unroll
        for (int r = 0; r < 4; ++r) {
            const int m = m0 + mw + (mf << 4) + (quad << 2) + r;
            const float bm = bias[m];
            const size_t row = outb + (size_t)m * N_PIX;
            #pragma unroll
            for (int nf = 0; nf < 8; ++nf) {
                const int p = p0 + nw + (nf << 4) + l16;
                float v = acc[mf][nf][r] + bm;
                if (MODE == 1) v = 0.5f * v * (1.0f + erff(v * 0.70710678118654752f));
                if (MODE == 2) v += R1[row + p] + R2[row + p];
                Y[row + p] = v;
            }
        }
    }
}

// ---------------------------------------------------------------------------
// Token sum-of-squares. norms[src][b][n][dir*128+t], atomic accumulate.
// ---------------------------------------------------------------------------
__global__ __launch_bounds__(256)
void norms_kernel(const float* __restrict__ out1, const float* __restrict__ out2,
                  float* __restrict__ norms)
{
    __shared__ float hsum[128];
    __shared__ float wsum[128];
    const int tid = threadIdx.x;
    const int b = blockIdx.x, n = blockIdx.y;
    const int src = blockIdx.z >> 2, qt = blockIdx.z & 3;
    const float* basep = (src == 0 ? out1 : out2)
        + (size_t)b * C_DIM * N_PIX + (size_t)n * C_PH * N_PIX + (size_t)(qt * 6) * N_PIX;

    if (tid < 128) hsum[tid] = 0.0f;
    __syncthreads();

    const int tx = tid & 127, ty = tid >> 7;
    float accw = 0.0f;
    for (int hh = 0; hh < 64; ++hh) {
        const int h = (hh << 1) + ty;
        float rowacc = 0.0f;
        #pragma unroll
        for (int ch = 0; ch < 6; ++ch) {
            const float v = basep[(size_t)ch * N_PIX + h * W_DIM + tx];
            rowacc += v * v;
        }
        accw += rowacc;
        #pragma unroll
        for (int off = 32; off > 0; off >>= 1) rowacc += __shfl_down(rowacc, off);
        if ((tid & 63) == 0) atomicAdd(&hsum[h], rowacc);
    }
    if (ty == 0) wsum[tx] = accw;
    __syncthreads();
    if (ty == 1) wsum[tx] += accw;
    __syncthreads();

    float* np_ = norms + ((size_t)(src * 8 + b) * 8 + n) * 256;
    if (tid < 128) atomicAdd(&np_[tid], hsum[tid]);
    else           atomicAdd(&np_[tid], wsum[tid - 128]);
}

// ---------------------------------------------------------------------------
// scores: partial raw S (fp32 VALU — precision-critical path, MFMA next round).
// grid (4 kc, 64 bn, 2 dir), block 256, 8x8/thread.
// ---------------------------------------------------------------------------
__global__ __launch_bounds__(256)
void scores_kernel(const float* __restrict__ out1, const float* __restrict__ out2,
                   float* __restrict__ Spart)
{
    __shared__ __align__(16) float Qs[16][132];
    __shared__ __align__(16) float Ks[16][132];

    const int tid = threadIdx.x;
    const int kc  = blockIdx.x;
    const int bn  = blockIdx.y;
    const int dir = blockIdx.z;
    const int b = bn >> 3, n = bn & 7;

    const size_t base = (size_t)b * C_DIM * N_PIX + (size_t)n * C_PH * N_PIX;
    const float* Qt = (dir == 0 ? out2 : out1) + base;
    const float* Kt = (dir == 0 ? out1 : out2) + base;

    const int ti = tid & 15, tj = tid >> 4;
    float acc[8][8] = {};

    for (int kt = 0; kt < 48; ++kt) {
        const int ch = kc * 6 + (kt >> 3);
        const int x0 = (kt & 7) << 4;
        const float* Qc = Qt + (size_t)ch * N_PIX;
        const float* Kc = Kt + (size_t)ch * N_PIX;

        if (dir == 0) {
            const int ib = tid >> 2, xg = (tid & 3) << 2;
            #pragma unroll
            for (int r = 0; r < 2; ++r) {
                const int ii = ib + (r << 6);
                const float4 q = *(const float4*)(Qc + (size_t)ii * W_DIM + x0 + xg);
                Qs[xg + 0][ii] = q.x; Qs[xg + 1][ii] = q.y;
                Qs[xg + 2][ii] = q.z; Qs[xg + 3][ii] = q.w;
                const float4 k = *(const float4*)(Kc + (size_t)ii * W_DIM + x0 + xg);
                Ks[xg + 0][ii] = k.x; Ks[xg + 1][ii] = k.y;
                Ks[xg + 2][ii] = k.z; Ks[xg + 3][ii] = k.w;
            }
        } else {
            const int kk = tid >> 5, ic = (tid & 31) << 2;
            #pragma unroll
            for (int r = 0; r < 2; ++r) {
                const int kr = kk + (r << 3);
                *(float4*)(&Qs[kr][ic]) = *(const float4*)(Qt + (size_t)ch * N_PIX + (size_t)(x0 + kr) * W_DIM + ic);
                *(float4*)(&Ks[kr][ic]) = *(const float4*)(Kt + (size_t)ch * N_PIX + (size_t)(x0 + kr) * W_DIM + ic);
            }
        }
        __syncthreads();

        #pragma unroll
        for (int kk = 0; kk < 16; ++kk) {
            float qa[8], ka[8];
            *(float4*)(&qa[0]) = *(const float4*)(&Qs[kk][(ti << 3) + 0]);
            *(float4*)(&qa[4]) = *(const float4*)(&Qs[kk][(ti << 3) + 4]);
            *(float4*)(&ka[0]) = *(const float4*)(&Ks[kk][(tj << 3) + 0]);
            *(float4*)(&ka[4]) = *(const float4*)(&Ks[kk][(tj << 3) + 4]);
            #pragma unroll
            for (int ii = 0; ii < 8; ++ii)
                #pragma unroll
                for (int jj = 0; jj < 8; ++jj)
                    acc[ii][jj] += qa[ii] * ka[jj];
        }
        __syncthreads();
    }

    float* Sp = Spart + ((((size_t)kc * 2 + dir) * 64 + bn) << 14);
    #pragma unroll
    for (int ii = 0; ii < 8; ++ii) {
        const int i = (ti << 3) + ii;
        *(float4*)(Sp + (size_t)i * 128 + (tj << 3) + 0) = *(float4*)(&acc[ii][0]);
        *(float4*)(Sp + (size_t)i * 128 + (tj << 3) + 4) = *(float4*)(&acc[ii][4]);
    }
}

// ---------------------------------------------------------------------------
// softmax: sum 4 partials, scale 100*rq*rk, softmax rows, pre-scale by gate
// weight, write P (fp32). grid (16 rowgroups, 64 bn, 2 dir), block 256.
// ---------------------------------------------------------------------------
__global__ __launch_bounds__(256)
void softmax_kernel(const float* __restrict__ Spart, float* __restrict__ P,
                    const float* __restrict__ norms, const float* __restrict__ gate)
{
    const int tid = threadIdx.x;
    const int bn  = blockIdx.y;
    const int dir = blockIdx.z;
    const int b = bn >> 3, n = bn & 7;

    const int r  = tid >> 5;
    const int j0 = (tid & 31) << 2;
    const int i  = (blockIdx.x << 3) + r;

    const int qsrc = (dir == 0) ? 1 : 0;
    const float* qn = norms + (((size_t)qsrc * 8 + b) * 8 + n) * 256 + dir * 128;
    const float* kn = norms + (((size_t)(1 - qsrc) * 8 + b) * 8 + n) * 256 + dir * 128;

    const float crow = TINV * rsqrtf(fmaxf(qn[i], 1e-24f));
    float rk[4];
    #pragma unroll
    for (int e = 0; e < 4; ++e) rk[e] = rsqrtf(fmaxf(kn[j0 + e], 1e-24f));

    const size_t off = ((size_t)dir * 64 + bn) * 16384 + (size_t)i * 128 + j0;
    float4 s = *(const float4*)(Spart + off);
    #pragma unroll
    for (int kc = 1; kc < 4; ++kc) {
        const float4 t = *(const float4*)(Spart + ((size_t)kc * 2 * 64 << 14) + off);
        s.x += t.x; s.y += t.y; s.z += t.z; s.w += t.w;
    }
    float v[4] = {s.x * crow * rk[0], s.y * crow * rk[1],
                  s.z * crow * rk[2], s.w * crow * rk[3]};

    float m = fmaxf(fmaxf(v[0], v[1]), fmaxf(v[2], v[3]));
    #pragma unroll
    for (int off2 = 16; off2 > 0; off2 >>= 1) m = fmaxf(m, __shfl_xor(m, off2));
    float e4[4], sum = 0.0f;
    #pragma unroll
    for (int e = 0; e < 4; ++e) { e4[e] = __expf(v[e] - m); sum += e4[e]; }
    #pragma unroll
    for (int off2 = 16; off2 > 0; off2 >>= 1) sum += __shfl_xor(sum, off2);

    const float g = 1.0f / (1.0f + __expf(-gate[0]));
    const float gs = (dir == 0) ? g : (1.0f - g);
    const float inv = gs / sum;

    float4 p = {e4[0] * inv, e4[1] * inv, e4[2] * inv, e4[3] * inv};
    *(float4*)(P + ((size_t)dir * 64 + bn) * 16384 + (size_t)i * 128 + j0) = p;
}

// ---------------------------------------------------------------------------
// pv via bf16 MFMA: per (ch, bn) plane,
//   F[i][w] = (P1g @ A1)[i][w] + (A2 @ P2g^T)[i][w]
//             + g*rq1[i]*A2[i][w] + (1-g)*rq2[w]*A1[i][w]
// P1g/P2g carry gate factors (from softmax). In-place over out1's plane.
// A-ops: P1 [i][j], A2 [i][j=w] (both k-contig). B-ops: P2 [w][j] natural,
// A1 needs [w][h] transpose (4x4 register transpose).
// grid (24 ch, 64 bn), block 256 (4 waves x 32 i-rows).
// ---------------------------------------------------------------------------
__global__ __launch_bounds__(256)
void pv_mfma(float* __restrict__ out1, const float* __restrict__ out2,
             const float* __restrict__ P, const float* __restrict__ norms,
             const float* __restrict__ gate)
{
    __shared__ unsigned short P1s[128][40];
    __shared__ unsigned short A2s[128][40];
    __shared__ unsigned short P2s[128][40];
    __shared__ unsigned short A1Ts[128][40];
    __shared__ float rqs[256];

    const int tid = threadIdx.x;
    const int ch  = blockIdx.x;
    const int bn  = blockIdx.y;
    const int b = bn >> 3, n = bn & 7;

    const size_t pbase = (size_t)b * C_DIM * N_PIX + ((size_t)n * C_PH + ch) * N_PIX;
    float* A1 = out1 + pbase;
    const float* A2 = out2 + pbase;
    const float* P1 = P + ((size_t)bn << 14);
    const float* P2 = P + ((size_t)(64 + bn) << 14);

    const float g = 1.0f / (1.0f + __expf(-gate[0]));
    if (tid < 128)
        rqs[tid] = g * rsqrtf(fmaxf(norms[(((size_t)8 + b) * 8 + n) * 256 + tid], 1e-24f));
    else
        rqs[tid] = (1.0f - g) * rsqrtf(fmaxf(norms[(((size_t)b) * 8 + n) * 256 + 128 + (tid - 128)], 1e-24f));

    const int wave = tid >> 6, lane = tid & 63;
    const int quad = lane >> 4, l16 = lane & 15;
    const int i0w = wave << 5;
    const int koff = quad << 3;

    f32x4 acc[2][8];
    #pragma unroll
    for (int i = 0; i < 2; ++i)
        #pragma unroll
        for (int j = 0; j < 8; ++j) acc[i][j] = (f32x4){0.f, 0.f, 0.f, 0.f};

    for (int k0 = 0; k0 < 128; k0 += 32) {
        // natural-layout tiles: P1, A2, P2 (row-major, k-contig)
        #pragma unroll
        for (int r = 0; r < 4; ++r) {
            const int v = tid + (r << 8);
            const int row = v >> 3, kq = v & 7;
            const size_t goff = (size_t)row * 128 + k0 + (kq << 2);
            float4 x;
            uint2 pk;
            x = *(const float4*)(P1 + goff);
            pk.x = pack2(f2bf(x.x), f2bf(x.y)); pk.y = pack2(f2bf(x.z), f2bf(x.w));
            *(uint2*)(&P1s[row][kq << 2]) = pk;
            x = *(const float4*)(A2 + goff);
            pk.x = pack2(f2bf(x.x), f2bf(x.y)); pk.y = pack2(f2bf(x.z), f2bf(x.w));
            *(uint2*)(&A2s[row][kq << 2]) = pk;
            x = *(const float4*)(P2 + goff);
            pk.x = pack2(f2bf(x.x), f2bf(x.y)); pk.y = pack2(f2bf(x.z), f2bf(x.w));
            *(uint2*)(&P2s[row][kq << 2]) = pk;
        }
        // A1 transpose tile: [w][h] from [h][w]
        {
            const int w4 = (tid & 31) << 2, jq = tid >> 5;
            float4 f[4];
            #pragma unroll
            for (int i = 0; i < 4; ++i)
                f[i] = *(const float4*)(A1 + (size_t)(k0 + (jq << 2) + i) * 128 + w4);
            #pragma unroll
            for (int j = 0; j < 4; ++j) {
                uint2 pk;
                pk.x = pack2(f2bf((&f[0].x)[j]), f2bf((&f[1].x)[j]));
                pk.y = pack2(f2bf((&f[2].x)[j]), f2bf((&f[3].x)[j]));
                *(uint2*)(&A1Ts[w4 + j][jq << 2]) = pk;
            }
        }
        __syncthreads();

        bf16x8 p1f[2], a2f[2];
        #pragma unroll
        for (int mf = 0; mf < 2; ++mf) {
            p1f[mf] = *(const bf16x8*)(&P1s[i0w + (mf << 4) + l16][koff]);
            a2f[mf] = *(const bf16x8*)(&A2s[i0w + (mf << 4) + l16][koff]);
        }
        #pragma unroll
        for (int nf = 0; nf < 8; ++nf) {
            const bf16x8 b1 = *(const bf16x8*)(&A1Ts[(nf << 4) + l16][koff]);
            const bf16x8 b2 = *(const bf16x8*)(&P2s[(nf << 4) + l16][koff]);
            #pragma unroll
            for (int mf = 0; mf < 2; ++mf) {
                acc[mf][nf] = __builtin_amdgcn_mfma_f32_16x16x32_bf16(p1f[mf], b1, acc[mf][nf], 0, 0, 0);
                acc[mf][nf] = __builtin_amdgcn_mfma_f32_16x16x32_bf16(a2f[mf], b2, acc[mf][nf], 0, 0, 0);
            }
        }
        __syncthreads();
    }

    // epilogue: + g*rq1[i]*A2 + (1-g)*rq2[w]*A1, write in place (element owned
    // by exactly one thread; all LDS staging reads completed before this point)
    #pragma unroll
    for (int mf = 0; mf < 2; ++mf) {
        #pragma unroll
        for (int r = 0; r < 4; ++r) {
            const int i = i0w + (mf << 4) + (quad << 2) + r;
            const float c1 = rqs[i];
            #pragma unroll
            for (int nf = 0; nf < 8; ++nf) {
                const int w = (nf << 4) + l16;
                const size_t o = (size_t)i * 128 + w;
                const float F = acc[mf][nf][r] + c1 * A2[o] + rqs[128 + w] * A1[o];
                A1[o] = F;
            }
        }
    }
}

// ---------------------------------------------------------------------------
extern "C" void kernel_launch(void* const* d_in, const int* in_sizes, int n_in,
                              void* d_out, int out_size, void* d_ws, size_t ws_size,
                              hipStream_t stream)
{
    (void)in_sizes; (void)n_in; (void)out_size; (void)ws_size;
    const float* x1     = (const float*)d_in[0];
    const float* x2     = (const float*)d_in[1];
    const float* W_proj = (const float*)d_in[2];
    const float* b_proj = (const float*)d_in[3];
    const float* gate   = (const float*)d_in[4];
    // d_in[5], d_in[6]: pos_bias_h/w — per-head scalars, cancel in softmax.
    const float* W_m1   = (const float*)d_in[7];
    const float* b_m1   = (const float*)d_in[8];
    const float* W_m2   = (const float*)d_in[9];
    const float* b_m2   = (const float*)d_in[10];

    float* ws0   = (float*)d_ws;          // out1 -> fusion (in place) -> t2
    float* ws1   = ws0 + ELEMS;           // out2 -> t1
    float* norms = ws1 + ELEMS;           // 32768 floats sumsq

    float* Spart = (float*)d_out;         // 4*2*64*16384 floats (32MB)
    float* Pbuf  = Spart + 8388608;       // 2*64*16384 floats (8MB)

    const dim3 cgrid(64, 3, 8);
    conv_mfma<0, 1><<<cgrid, 256, 0, stream>>>(x1, W_proj, b_proj, ws0, nullptr, nullptr);
    conv_mfma<0, 1><<<cgrid, 256, 0, stream>>>(x2, W_proj, b_proj, ws1, nullptr, nullptr);

    hipMemsetAsync(norms, 0, 32768 * sizeof(float), stream);
    norms_kernel<<<dim3(8, 8, 8), 256, 0, stream>>>(ws0, ws1, norms);

    scores_kernel<<<dim3(4, 64, 2), 256, 0, stream>>>(ws0, ws1, Spart);
    softmax_kernel<<<dim3(16, 64, 2), 256, 0, stream>>>(Spart, Pbuf, norms, gate);
    pv_mfma<<<dim3(24, 64), 256, 0, stream>>>(ws0, ws1, Pbuf, norms, gate);

    conv_mfma<0, 0><<<cgrid, 256, 0, stream>>>(ws0, W_proj, b_proj, ws1, nullptr, nullptr);
    conv_mfma<1, 0><<<cgrid, 256, 0, stream>>>(ws1, W_m1, b_m1, ws0, nullptr, nullptr);
    conv_mfma<2, 0><<<cgrid, 256, 0, stream>>>(ws0, W_m2, b_m2, (float*)d_out, x1, x2);
}

// Round 4
// 604.659 us; speedup vs baseline: 2.8063x; 1.3921x over previous
//
#include <hip/hip_runtime.h>
#include <math.h>

// BCAM: x1,x2 [8,192,128,128] f32. heads=8, c=24, temperature=0.01.
// R4: all-bf16 MFMA pipeline.
//   conv1/2 (f32 in -> bf16 out), norms (bf16 in),
//   scores+softmax fused (bf16 MFMA, full K, P bf16 w/ gate pre-scale),
//   pv (all-bf16 staging, fusion bf16 -> d_out scratch),
//   conv5/6/7 (bf16 in; conv7 -> f32 d_out + x1 + x2).
// Numerics: bf16 rounding errors enter logits as ~100*3e-3/sqrt(3072) ~ 0.005
// (RMS, random-sign) — far below the 0.152 threshold. R3 evidence: bf16 P/V
// left absmax unchanged at 0.03125.
// pos_bias dropped (per-head scalar, softmax shift-invariant).
// V = UNNORMALIZED tokens (v1=k1 binds before l2norm).

#define N_PIX 16384
#define W_DIM 128
#define C_DIM 192
#define C_PH  24
#define ELEMS 25165824  // 8*192*128*128
#define TINV  100.0f

typedef __bf16 bf16x8 __attribute__((ext_vector_type(8)));
typedef float  f32x4  __attribute__((ext_vector_type(4)));

__device__ __forceinline__ unsigned short f2bf(float f) {
    union { float f; unsigned u; } x; x.f = f;
    unsigned r = x.u + 0x7FFF + ((x.u >> 16) & 1);
    return (unsigned short)(r >> 16);
}
__device__ __forceinline__ float bf2f(unsigned short h) {
    union { unsigned u; float f; } x; x.u = ((unsigned)h) << 16; return x.f;
}
__device__ __forceinline__ unsigned pack2(unsigned short a, unsigned short b) {
    return (unsigned)a | ((unsigned)b << 16);
}

// ---------------------------------------------------------------------------
// conv1x1, f32 input -> bf16 output (conv1/conv2).
// grid (64 p-tiles, 3 m-tiles, 8 b), block 256. Tile 64m x 256p.
// ---------------------------------------------------------------------------
__global__ __launch_bounds__(256)
void conv_f32in(const float* __restrict__ X, const float* __restrict__ Wt,
                const float* __restrict__ bias, unsigned short* __restrict__ Y)
{
    __shared__ unsigned short Ah[64][40];
    __shared__ unsigned short Bh[256][40];

    const int tid = threadIdx.x;
    const int p0 = blockIdx.x << 8;
    const int m0 = blockIdx.y << 6;
    const int b  = blockIdx.z;
    const float* Xb = X + (size_t)b * C_DIM * N_PIX;

    const int wave = tid >> 6, lane = tid & 63;
    const int quad = lane >> 4, l16 = lane & 15;
    const int mw = (wave & 1) << 5;
    const int nw = (wave >> 1) << 7;
    const int koff = quad << 3;

    f32x4 acc[2][8];
    #pragma unroll
    for (int i = 0; i < 2; ++i)
        #pragma unroll
        for (int j = 0; j < 8; ++j) acc[i][j] = (f32x4){0.f, 0.f, 0.f, 0.f};

    for (int k0 = 0; k0 < C_DIM; k0 += 32) {
        // A (weights) 64m x 32k
        #pragma unroll
        for (int i = 0; i < 2; ++i) {
            const int a = (tid << 1) + i;
            const int m = a >> 3, kq = a & 7;
            const float4 v = *(const float4*)(Wt + (size_t)(m0 + m) * C_DIM + k0 + (kq << 2));
            uint2 pk; pk.x = pack2(f2bf(v.x), f2bf(v.y)); pk.y = pack2(f2bf(v.z), f2bf(v.w));
            *(uint2*)(&Ah[m][kq << 2]) = pk;
        }
        // B (pixels) 32k x 256p, 4x4 transpose. kq in low bits -> spread banks.
        #pragma unroll
        for (int r = 0; r < 2; ++r) {
            const int u = tid + (r << 8);
            const int kq = u & 7, p4 = (u >> 3) << 2;
            float4 f[4];
            #pragma unroll
            for (int i = 0; i < 4; ++i)
                f[i] = *(const float4*)(Xb + (size_t)(k0 + (kq << 2) + i) * N_PIX + p0 + p4);
            #pragma unroll
            for (int j = 0; j < 4; ++j) {
                uint2 pk;
                pk.x = pack2(f2bf((&f[0].x)[j]), f2bf((&f[1].x)[j]));
                pk.y = pack2(f2bf((&f[2].x)[j]), f2bf((&f[3].x)[j]));
                *(uint2*)(&Bh[p4 + j][kq << 2]) = pk;
            }
        }
        __syncthreads();

        bf16x8 af[2];
        #pragma unroll
        for (int mf = 0; mf < 2; ++mf)
            af[mf] = *(const bf16x8*)(&Ah[mw + (mf << 4) + l16][koff]);
        #pragma unroll
        for (int nf = 0; nf < 8; ++nf) {
            const bf16x8 bfr = *(const bf16x8*)(&Bh[nw + (nf << 4) + l16][koff]);
            #pragma unroll
            for (int mf = 0; mf < 2; ++mf)
                acc[mf][nf] = __builtin_amdgcn_mfma_f32_16x16x32_bf16(af[mf], bfr, acc[mf][nf], 0, 0, 0);
        }
        __syncthreads();
    }

    const size_t outb = (size_t)b * C_DIM * N_PIX;
    #pragma unroll
    for (int mf = 0; mf < 2; ++mf) {
        #pragma unroll
        for (int r = 0; r < 4; ++r) {
            const int m = m0 + mw + (mf << 4) + (quad << 2) + r;
            const float bm = bias[m];
            const size_t row = outb + (size_t)m * N_PIX;
            #pragma unroll
            for (int nf = 0; nf < 8; ++nf) {
                const int p = p0 + nw + (nf << 4) + l16;
                Y[row + p] = f2bf(acc[mf][nf][r] + bm);
            }
        }
    }
}

// ---------------------------------------------------------------------------
// conv1x1, bf16 input (conv5/6/7). MODE 0: bf16 out; 1: GELU, bf16 out;
// 2: + R1 + R2 (f32), f32 out.
// ---------------------------------------------------------------------------
template<int MODE>
__global__ __launch_bounds__(256)
void conv_b16in(const unsigned short* __restrict__ X, const float* __restrict__ Wt,
                const float* __restrict__ bias, void* __restrict__ Yv,
                const float* __restrict__ R1, const float* __restrict__ R2)
{
    __shared__ unsigned short Ah[64][40];
    __shared__ unsigned short Bh[256][40];

    const int tid = threadIdx.x;
    const int p0 = blockIdx.x << 8;
    const int m0 = blockIdx.y << 6;
    const int b  = blockIdx.z;
    const unsigned short* Xb = X + (size_t)b * C_DIM * N_PIX;

    const int wave = tid >> 6, lane = tid & 63;
    const int quad = lane >> 4, l16 = lane & 15;
    const int mw = (wave & 1) << 5;
    const int nw = (wave >> 1) << 7;
    const int koff = quad << 3;

    f32x4 acc[2][8];
    #pragma unroll
    for (int i = 0; i < 2; ++i)
        #pragma unroll
        for (int j = 0; j < 8; ++j) acc[i][j] = (f32x4){0.f, 0.f, 0.f, 0.f};

    for (int k0 = 0; k0 < C_DIM; k0 += 32) {
        #pragma unroll
        for (int i = 0; i < 2; ++i) {
            const int a = (tid << 1) + i;
            const int m = a >> 3, kq = a & 7;
            const float4 v = *(const float4*)(Wt + (size_t)(m0 + m) * C_DIM + k0 + (kq << 2));
            uint2 pk; pk.x = pack2(f2bf(v.x), f2bf(v.y)); pk.y = pack2(f2bf(v.z), f2bf(v.w));
            *(uint2*)(&Ah[m][kq << 2]) = pk;
        }
        // B: 32k x 256p. Thread: 4 k-rows (kq) x 8 p. Pure ushort transpose.
        {
            const int kq = tid & 7, pg = (tid >> 3) << 3;
            uint4 f[4];
            #pragma unroll
            for (int i = 0; i < 4; ++i)
                f[i] = *(const uint4*)(Xb + (size_t)(k0 + (kq << 2) + i) * N_PIX + p0 + pg);
            #pragma unroll
            for (int j = 0; j < 8; ++j) {
                const unsigned short e0 = ((const unsigned short*)&f[0])[j];
                const unsigned short e1 = ((const unsigned short*)&f[1])[j];
                const unsigned short e2 = ((const unsigned short*)&f[2])[j];
                const unsigned short e3 = ((const unsigned short*)&f[3])[j];
                uint2 pk; pk.x = pack2(e0, e1); pk.y = pack2(e2, e3);
                *(uint2*)(&Bh[pg + j][kq << 2]) = pk;
            }
        }
        __syncthreads();

        bf16x8 af[2];
        #pragma unroll
        for (int mf = 0; mf < 2; ++mf)
            af[mf] = *(const bf16x8*)(&Ah[mw + (mf << 4) + l16][koff]);
        #pragma unroll
        for (int nf = 0; nf < 8; ++nf) {
            const bf16x8 bfr = *(const bf16x8*)(&Bh[nw + (nf << 4) + l16][koff]);
            #pragma unroll
            for (int mf = 0; mf < 2; ++mf)
                acc[mf][nf] = __builtin_amdgcn_mfma_f32_16x16x32_bf16(af[mf], bfr, acc[mf][nf], 0, 0, 0);
        }
        __syncthreads();
    }

    const size_t outb = (size_t)b * C_DIM * N_PIX;
    #pragma unroll
    for (int mf = 0; mf < 2; ++mf) {
        #pragma unroll
        for (int r = 0; r < 4; ++r) {
            const int m = m0 + mw + (mf << 4) + (quad << 2) + r;
            const float bm = bias[m];
            const size_t row = outb + (size_t)m * N_PIX;
            #pragma unroll
            for (int nf = 0; nf < 8; ++nf) {
                const int p = p0 + nw + (nf << 4) + l16;
                float v = acc[mf][nf][r] + bm;
                if (MODE == 1) v = 0.5f * v * (1.0f + erff(v * 0.70710678118654752f));
                if (MODE == 2) {
                    v += R1[row + p] + R2[row + p];
                    ((float*)Yv)[row + p] = v;
                } else {
                    ((unsigned short*)Yv)[row + p] = f2bf(v);
                }
            }
        }
    }
}

// ---------------------------------------------------------------------------
// Token sum-of-squares from bf16 out1/out2. norms[src][b][n][dir*128+t].
// ---------------------------------------------------------------------------
__global__ __launch_bounds__(256)
void norms_kernel(const unsigned short* __restrict__ o1,
                  const unsigned short* __restrict__ o2,
                  float* __restrict__ norms)
{
    __shared__ float hsum[128];
    __shared__ float wsum[128];
    const int tid = threadIdx.x;
    const int b = blockIdx.x, n = blockIdx.y;
    const int src = blockIdx.z >> 2, qt = blockIdx.z & 3;
    const unsigned short* basep = (src == 0 ? o1 : o2)
        + (size_t)b * C_DIM * N_PIX + (size_t)n * C_PH * N_PIX + (size_t)(qt * 6) * N_PIX;

    if (tid < 128) hsum[tid] = 0.0f;
    __syncthreads();

    const int tx = tid & 127, ty = tid >> 7;
    float accw = 0.0f;
    for (int hh = 0; hh < 64; ++hh) {
        const int h = (hh << 1) + ty;
        float rowacc = 0.0f;
        #pragma unroll
        for (int ch = 0; ch < 6; ++ch) {
            const float v = bf2f(basep[(size_t)ch * N_PIX + h * W_DIM + tx]);
            rowacc += v * v;
        }
        accw += rowacc;
        #pragma unroll
        for (int off = 32; off > 0; off >>= 1) rowacc += __shfl_down(rowacc, off);
        if ((tid & 63) == 0) atomicAdd(&hsum[h], rowacc);
    }
    if (ty == 0) wsum[tx] = accw;
    __syncthreads();
    if (ty == 1) wsum[tx] += accw;
    __syncthreads();

    float* np_ = norms + ((size_t)(src * 8 + b) * 8 + n) * 256;
    if (tid < 128) atomicAdd(&np_[tid], hsum[tid]);
    else           atomicAdd(&np_[tid], wsum[tid - 128]);
}

// ---------------------------------------------------------------------------
// Fused scores+softmax: S = Qbf.Kbf^T (full K=3072), scale 100*rq*rk, row
// softmax, pre-scale by gate weight, write P bf16.
// grid (2 i-tiles, 64 bn, 2 dir), block 256 (4 waves x 16 i-rows).
// ---------------------------------------------------------------------------
__global__ __launch_bounds__(256)
void scores_softmax(const unsigned short* __restrict__ o1,
                    const unsigned short* __restrict__ o2,
                    const float* __restrict__ norms, const float* __restrict__ gate,
                    unsigned short* __restrict__ P)
{
    __shared__ unsigned short Qh[64][40];
    __shared__ unsigned short Kh[128][40];
    __shared__ float rqv[64], rkv[128];

    const int tid = threadIdx.x;
    const int i0  = blockIdx.x << 6;
    const int bn  = blockIdx.y;
    const int dir = blockIdx.z;
    const int b = bn >> 3, n = bn & 7;

    const size_t base = (size_t)b * C_DIM * N_PIX + (size_t)n * C_PH * N_PIX;
    const unsigned short* Qb = (dir == 0 ? o2 : o1) + base;
    const unsigned short* Kb = (dir == 0 ? o1 : o2) + base;

    const int qsrc = (dir == 0) ? 1 : 0;
    const float* qn_g = norms + ((size_t)(qsrc * 8 + b) * 8 + n) * 256 + dir * 128;
    const float* kn_g = norms + ((size_t)((1 - qsrc) * 8 + b) * 8 + n) * 256 + dir * 128;

    if (tid < 64)        rqv[tid]      = TINV * rsqrtf(fmaxf(qn_g[i0 + tid], 1e-24f));
    else if (tid < 192)  rkv[tid - 64] = rsqrtf(fmaxf(kn_g[tid - 64], 1e-24f));

    const int wave = tid >> 6, lane = tid & 63;
    const int quad = lane >> 4, l16 = lane & 15;
    const int koff = quad << 3;

    f32x4 acc[8];
    #pragma unroll
    for (int j = 0; j < 8; ++j) acc[j] = (f32x4){0.f, 0.f, 0.f, 0.f};

    for (int ks = 0; ks < 96; ++ks) {
        const int ch = ks >> 2;
        const int x0 = (ks & 3) << 5;
        const size_t cb = (size_t)ch * N_PIX;

        if (dir == 0) {
            // tokens = h-rows, k along w: natural k-contiguous rows.
            {   // Q: 64 rows x 32k = 256 uint4
                const int row = tid >> 2, q4 = tid & 3;
                *(uint4*)(&Qh[row][q4 << 3]) =
                    *(const uint4*)(Qb + cb + (size_t)(i0 + row) * W_DIM + x0 + (q4 << 3));
            }
            #pragma unroll
            for (int r = 0; r < 2; ++r) {  // K: 128 rows x 32k = 512 uint4
                const int u = tid + (r << 8);
                const int row = u >> 2, q4 = u & 3;
                *(uint4*)(&Kh[row][q4 << 3]) =
                    *(const uint4*)(Kb + cb + (size_t)row * W_DIM + x0 + (q4 << 3));
            }
        } else {
            // tokens = w-cols, k along h: 4x8 ushort transpose.
            if (tid < 64) {         // Q: 8 wgroups x 8 kq
                const int wg = tid >> 3, kq = tid & 7;
                uint4 f[4];
                #pragma unroll
                for (int i = 0; i < 4; ++i)
                    f[i] = *(const uint4*)(Qb + cb + (size_t)(x0 + (kq << 2) + i) * W_DIM + i0 + (wg << 3));
                #pragma unroll
                for (int j = 0; j < 8; ++j) {
                    uint2 pk;
                    pk.x = pack2(((const unsigned short*)&f[0])[j], ((const unsigned short*)&f[1])[j]);
                    pk.y = pack2(((const unsigned short*)&f[2])[j], ((const unsigned short*)&f[3])[j]);
                    *(uint2*)(&Qh[(wg << 3) + j][kq << 2]) = pk;
                }
            } else if (tid < 192) { // K: 16 wgroups x 8 kq
                const int u = tid - 64;
                const int wg = u >> 3, kq = u & 7;
                uint4 f[4];
                #pragma unroll
                for (int i = 0; i < 4; ++i)
                    f[i] = *(const uint4*)(Kb + cb + (size_t)(x0 + (kq << 2) + i) * W_DIM + (wg << 3));
                #pragma unroll
                for (int j = 0; j < 8; ++j) {
                    uint2 pk;
                    pk.x = pack2(((const unsigned short*)&f[0])[j], ((const unsigned short*)&f[1])[j]);
                    pk.y = pack2(((const unsigned short*)&f[2])[j], ((const unsigned short*)&f[3])[j]);
                    *(uint2*)(&Kh[(wg << 3) + j][kq << 2]) = pk;
                }
            }
        }
        __syncthreads();

        const bf16x8 a = *(const bf16x8*)(&Qh[(wave << 4) + l16][koff]);
        #pragma unroll
        for (int nf = 0; nf < 8; ++nf) {
            const bf16x8 bfr = *(const bf16x8*)(&Kh[(nf << 4) + l16][koff]);
            acc[nf] = __builtin_amdgcn_mfma_f32_16x16x32_bf16(a, bfr, acc[nf], 0, 0, 0);
        }
        __syncthreads();
    }

    // softmax per row r: row i_loc = wave*16 + quad*4 + r, cols nf*16+l16.
    const float g = 1.0f / (1.0f + __expf(-gate[0]));
    const float gs = (dir == 0) ? g : (1.0f - g);
    unsigned short* Pg = P + (((size_t)dir * 64 + bn) << 14);

    #pragma unroll
    for (int r = 0; r < 4; ++r) {
        const int i_loc = (wave << 4) + (quad << 2) + r;
        const float rq = rqv[i_loc];
        float v[8], m = -1e30f;
        #pragma unroll
        for (int nf = 0; nf < 8; ++nf) {
            v[nf] = acc[nf][r] * rq * rkv[(nf << 4) + l16];
            m = fmaxf(m, v[nf]);
        }
        #pragma unroll
        for (int off = 1; off < 16; off <<= 1) m = fmaxf(m, __shfl_xor(m, off));
        float s = 0.0f;
        #pragma unroll
        for (int nf = 0; nf < 8; ++nf) { v[nf] = __expf(v[nf] - m); s += v[nf]; }
        #pragma unroll
        for (int off = 1; off < 16; off <<= 1) s += __shfl_xor(s, off);
        const float inv = gs / s;
        const size_t rowo = (size_t)(i0 + i_loc) * 128;
        #pragma unroll
        for (int nf = 0; nf < 8; ++nf)
            Pg[rowo + (nf << 4) + l16] = f2bf(v[nf] * inv);
    }
}

// ---------------------------------------------------------------------------
// pv: per (ch, bn) plane, F = P1g@A1 + A2@P2g^T + g*rq1[h]*A2 + (1-g)*rq2[w]*A1.
// All inputs bf16 (P carries gate factors). Output fusion bf16.
// grid (24 ch, 64 bn), block 256.
// ---------------------------------------------------------------------------
__global__ __launch_bounds__(256)
void pv_mfma(const unsigned short* __restrict__ o1, const unsigned short* __restrict__ o2,
             const unsigned short* __restrict__ P, const float* __restrict__ norms,
             const float* __restrict__ gate, unsigned short* __restrict__ fusion)
{
    __shared__ unsigned short P1s[128][40];
    __shared__ unsigned short A2s[128][40];
    __shared__ unsigned short P2s[128][40];
    __shared__ unsigned short A1Ts[128][40];
    __shared__ float rqs[256];

    const int tid = threadIdx.x;
    const int ch  = blockIdx.x;
    const int bn  = blockIdx.y;
    const int b = bn >> 3, n = bn & 7;

    const size_t pbase = (size_t)b * C_DIM * N_PIX + ((size_t)n * C_PH + ch) * N_PIX;
    const unsigned short* A1 = o1 + pbase;
    const unsigned short* A2 = o2 + pbase;
    const unsigned short* P1 = P + ((size_t)bn << 14);
    const unsigned short* P2 = P + ((size_t)(64 + bn) << 14);
    unsigned short* Fp = fusion + pbase;

    const float g = 1.0f / (1.0f + __expf(-gate[0]));
    if (tid < 128)
        rqs[tid] = g * rsqrtf(fmaxf(norms[(((size_t)8 + b) * 8 + n) * 256 + tid], 1e-24f));
    else
        rqs[tid] = (1.0f - g) * rsqrtf(fmaxf(norms[(((size_t)b) * 8 + n) * 256 + 128 + (tid - 128)], 1e-24f));

    const int wave = tid >> 6, lane = tid & 63;
    const int quad = lane >> 4, l16 = lane & 15;
    const int i0w = wave << 5;
    const int koff = quad << 3;

    f32x4 acc[2][8];
    #pragma unroll
    for (int i = 0; i < 2; ++i)
        #pragma unroll
        for (int j = 0; j < 8; ++j) acc[i][j] = (f32x4){0.f, 0.f, 0.f, 0.f};

    for (int k0 = 0; k0 < 128; k0 += 32) {
        // natural tiles: P1 [i][j], A2 [h][w], P2 [w][j] — pure uint4 copies
        #pragma unroll
        for (int r = 0; r < 2; ++r) {
            const int u = tid + (r << 8);
            const int row = u >> 2, k8 = u & 3;
            const size_t go = (size_t)row * 128 + k0 + (k8 << 3);
            *(uint4*)(&P1s[row][k8 << 3]) = *(const uint4*)(P1 + go);
            *(uint4*)(&A2s[row][k8 << 3]) = *(const uint4*)(A2 + go);
            *(uint4*)(&P2s[row][k8 << 3]) = *(const uint4*)(P2 + go);
        }
        // A1^T tile: [w][h] from [h][w], 4x8 ushort transpose (threads 0..127)
        if (tid < 128) {
            const int wg = tid >> 3, hq = tid & 7;
            uint4 f[4];
            #pragma unroll
            for (int i = 0; i < 4; ++i)
                f[i] = *(const uint4*)(A1 + (size_t)(k0 + (hq << 2) + i) * 128 + (wg << 3));
            #pragma unroll
            for (int j = 0; j < 8; ++j) {
                uint2 pk;
                pk.x = pack2(((const unsigned short*)&f[0])[j], ((const unsigned short*)&f[1])[j]);
                pk.y = pack2(((const unsigned short*)&f[2])[j], ((const unsigned short*)&f[3])[j]);
                *(uint2*)(&A1Ts[(wg << 3) + j][hq << 2]) = pk;
            }
        }
        __syncthreads();

        bf16x8 p1f[2], a2f[2];
        #pragma unroll
        for (int mf = 0; mf < 2; ++mf) {
            p1f[mf] = *(const bf16x8*)(&P1s[i0w + (mf << 4) + l16][koff]);
            a2f[mf] = *(const bf16x8*)(&A2s[i0w + (mf << 4) + l16][koff]);
        }
        #pragma unroll
        for (int nf = 0; nf < 8; ++nf) {
            const bf16x8 b1 = *(const bf16x8*)(&A1Ts[(nf << 4) + l16][koff]);
            const bf16x8 b2 = *(const bf16x8*)(&P2s[(nf << 4) + l16][koff]);
            #pragma unroll
            for (int mf = 0; mf < 2; ++mf) {
                acc[mf][nf] = __builtin_amdgcn_mfma_f32_16x16x32_bf16(p1f[mf], b1, acc[mf][nf], 0, 0, 0);
                acc[mf][nf] = __builtin_amdgcn_mfma_f32_16x16x32_bf16(a2f[mf], b2, acc[mf][nf], 0, 0, 0);
            }
        }
        __syncthreads();
    }

    #pragma unroll
    for (int mf = 0; mf < 2; ++mf) {
        #pragma unroll
        for (int r = 0; r < 4; ++r) {
            const int i = i0w + (mf << 4) + (quad << 2) + r;
            const float c1 = rqs[i];
            #pragma unroll
            for (int nf = 0; nf < 8; ++nf) {
                const int w = (nf << 4) + l16;
                const size_t o = (size_t)i * 128 + w;
                const float F = acc[mf][nf][r] + c1 * bf2f(A2[o]) + rqs[128 + w] * bf2f(A1[o]);
                Fp[o] = f2bf(F);
            }
        }
    }
}

// ---------------------------------------------------------------------------
extern "C" void kernel_launch(void* const* d_in, const int* in_sizes, int n_in,
                              void* d_out, int out_size, void* d_ws, size_t ws_size,
                              hipStream_t stream)
{
    (void)in_sizes; (void)n_in; (void)out_size; (void)ws_size;
    const float* x1     = (const float*)d_in[0];
    const float* x2     = (const float*)d_in[1];
    const float* W_proj = (const float*)d_in[2];
    const float* b_proj = (const float*)d_in[3];
    const float* gate   = (const float*)d_in[4];
    // d_in[5], d_in[6]: pos_bias_h/w — per-head scalars, cancel in softmax.
    const float* W_m1   = (const float*)d_in[7];
    const float* b_m1   = (const float*)d_in[8];
    const float* W_m2   = (const float*)d_in[9];
    const float* b_m2   = (const float*)d_in[10];

    unsigned short* o1    = (unsigned short*)d_ws;       // out1 bf16 -> t1
    unsigned short* o2    = o1 + ELEMS;                  // out2 bf16 -> t2
    float*          norms = (float*)(o2 + ELEMS);        // 32768 f32

    unsigned short* fusion = (unsigned short*)d_out;     // bf16, dead by conv7
    unsigned short* Pbuf   = fusion + ELEMS;             // 2*64*16384 bf16

    const dim3 cgrid(64, 3, 8);
    conv_f32in<<<cgrid, 256, 0, stream>>>(x1, W_proj, b_proj, o1);
    conv_f32in<<<cgrid, 256, 0, stream>>>(x2, W_proj, b_proj, o2);

    hipMemsetAsync(norms, 0, 32768 * sizeof(float), stream);
    norms_kernel<<<dim3(8, 8, 8), 256, 0, stream>>>(o1, o2, norms);

    scores_softmax<<<dim3(2, 64, 2), 256, 0, stream>>>(o1, o2, norms, gate, Pbuf);
    pv_mfma<<<dim3(24, 64), 256, 0, stream>>>(o1, o2, Pbuf, norms, gate, fusion);

    conv_b16in<0><<<cgrid, 256, 0, stream>>>(fusion, W_proj, b_proj, o1, nullptr, nullptr);
    conv_b16in<1><<<cgrid, 256, 0, stream>>>(o1, W_m1, b_m1, o2, nullptr, nullptr);
    conv_b16in<2><<<cgrid, 256, 0, stream>>>(o2, W_m2, b_m2, d_out, x1, x2);
}